// Round 1
// baseline (7005.249 us; speedup 1.0000x reference)
//
#include <hip/hip_runtime.h>
#include <math.h>

#define B_      4
#define C_      32
#define COND_   80
#define LMEL_   2048
#define HOP_    8
#define UP_     8
#define LAYERS_ 4
#define K_      3
#define HID_    64
#define KPK_    3
#define EMB_    512
#define LAUD_   (LMEL_*UP_)          // 16384
#define KCH_    (LAYERS_*C_*2*C_*K_) // 24576
#define BCH_    (LAYERS_*2*C_)       // 256

__device__ __forceinline__ float lrelu_(float v, float s) { return v >= 0.f ? v : s * v; }

// ---------------------------------------------------------------- K1: noise + condition
__global__ void k_noise_cond(const float* __restrict__ ne, const float* __restrict__ fw,
                             const float* __restrict__ fb, const float* __restrict__ c,
                             float* __restrict__ cond) {
  int b = blockIdx.x / COND_;
  int cc = blockIdx.x % COND_;
  __shared__ float red[256];
  float p = 0.f;
  for (int j = threadIdx.x; j < EMB_; j += 256)
    p += ne[b*EMB_ + j] * fw[cc*EMB_ + j];
  red[threadIdx.x] = p;
  __syncthreads();
  for (int s = 128; s > 0; s >>= 1) {
    if (threadIdx.x < s) red[threadIdx.x] += red[threadIdx.x + s];
    __syncthreads();
  }
  float noise = red[0] + fb[cc];
  const float* cp = c + (b*COND_ + cc)*LMEL_;
  float* op = cond + (b*COND_ + cc)*LMEL_;
  for (int l = threadIdx.x; l < LMEL_; l += 256) op[l] = cp[l] + noise;
}

// ---------------------------------------------------------------- K2: KP input conv (80->64, k=5, pad=2, lrelu 0.1)
__global__ __launch_bounds__(256) void k_kp_in(const float* __restrict__ cond, const float* __restrict__ w,
                                               const float* __restrict__ bias, float* __restrict__ out) {
  const int T = 64;
  int b  = blockIdx.x / (LMEL_/T);
  int lb = (blockIdx.x % (LMEL_/T)) * T;
  __shared__ float sc[COND_][T + 4];
  for (int idx = threadIdx.x; idx < COND_*(T+4); idx += 256) {
    int cc = idx / (T+4), j = idx % (T+4);
    int l = lb + j - 2;
    sc[cc][j] = (l >= 0 && l < LMEL_) ? cond[(b*COND_ + cc)*LMEL_ + l] : 0.f;
  }
  __syncthreads();
  int ch = threadIdx.x & 63;
  int lq = threadIdx.x >> 6;  // 0..3, 16 l's each
  float acc[16];
#pragma unroll
  for (int ii = 0; ii < 16; ii++) acc[ii] = bias[ch];
  const float* wr = w + ch*COND_*5;
  for (int cc = 0; cc < COND_; cc++) {
    float r[20];
#pragma unroll
    for (int j = 0; j < 20; j++) r[j] = sc[cc][lq*16 + j];
#pragma unroll
    for (int k = 0; k < 5; k++) {
      float wv = wr[cc*5 + k];
#pragma unroll
      for (int ii = 0; ii < 16; ii++) acc[ii] = fmaf(wv, r[ii + k], acc[ii]);
    }
  }
  float* op = out + (b*HID_ + ch)*LMEL_ + lb + lq*16;
#pragma unroll
  for (int ii = 0; ii < 16; ii++) op[ii] = lrelu_(acc[ii], 0.1f);
}

// ---------------------------------------------------------------- K3: KP res conv (64->64, k=3, pad=1, lrelu 0.1, opt residual)
__global__ __launch_bounds__(256) void k_kp_res(const float* __restrict__ in, const float* __restrict__ w,
                                                const float* __restrict__ bias, const float* __restrict__ res,
                                                float* __restrict__ out) {
  const int T = 64;
  int b  = blockIdx.x / (LMEL_/T);
  int lb = (blockIdx.x % (LMEL_/T)) * T;
  __shared__ float si[HID_][T + 2];
  for (int idx = threadIdx.x; idx < HID_*(T+2); idx += 256) {
    int cc = idx / (T+2), j = idx % (T+2);
    int l = lb + j - 1;
    si[cc][j] = (l >= 0 && l < LMEL_) ? in[(b*HID_ + cc)*LMEL_ + l] : 0.f;
  }
  __syncthreads();
  int ch = threadIdx.x & 63;
  int lq = threadIdx.x >> 6;
  float acc[16];
#pragma unroll
  for (int ii = 0; ii < 16; ii++) acc[ii] = bias[ch];
  const float* wr = w + ch*HID_*3;
  for (int cc = 0; cc < HID_; cc++) {
    float r[18];
#pragma unroll
    for (int j = 0; j < 18; j++) r[j] = si[cc][lq*16 + j];
#pragma unroll
    for (int k = 0; k < 3; k++) {
      float wv = wr[cc*3 + k];
#pragma unroll
      for (int ii = 0; ii < 16; ii++) acc[ii] = fmaf(wv, r[ii + k], acc[ii]);
    }
  }
  int lo = lb + lq*16;
  float* op = out + (b*HID_ + ch)*LMEL_ + lo;
  const float* rp = res ? res + (b*HID_ + ch)*LMEL_ + lo : nullptr;
#pragma unroll
  for (int ii = 0; ii < 16; ii++) {
    float v = lrelu_(acc[ii], 0.1f);
    if (rp) v += rp[ii];
    op[ii] = v;
  }
}

// ---------------------------------------------------------------- K4: bias conv (64->256, k=3, pad=1)
__global__ __launch_bounds__(256) void k_kp_bias(const float* __restrict__ in, const float* __restrict__ w,
                                                 const float* __restrict__ bias, float* __restrict__ out) {
  const int T = 32;
  int b  = blockIdx.x / (LMEL_/T);
  int lb = (blockIdx.x % (LMEL_/T)) * T;
  __shared__ float si[HID_][T + 2];
  for (int idx = threadIdx.x; idx < HID_*(T+2); idx += 256) {
    int cc = idx / (T+2), j = idx % (T+2);
    int l = lb + j - 1;
    si[cc][j] = (l >= 0 && l < LMEL_) ? in[(b*HID_ + cc)*LMEL_ + l] : 0.f;
  }
  __syncthreads();
  int ch = threadIdx.x;  // 0..255
  float acc[T];
  float bv = bias[ch];
#pragma unroll
  for (int ii = 0; ii < T; ii++) acc[ii] = bv;
  const float* wr = w + ch*HID_*3;
  for (int cc = 0; cc < HID_; cc++) {
    float w0 = wr[cc*3], w1 = wr[cc*3+1], w2 = wr[cc*3+2];
#pragma unroll
    for (int ii = 0; ii < T; ii++)
      acc[ii] = fmaf(w0, si[cc][ii], fmaf(w1, si[cc][ii+1], fmaf(w2, si[cc][ii+2], acc[ii])));
  }
  float* op = out + (b*BCH_ + ch)*LMEL_ + lb;
#pragma unroll
  for (int ii = 0; ii < T; ii++) op[ii] = acc[ii];
}

// ---------------------------------------------------------------- K5: upsample (conv_transpose1d stride 8, k=16, pad=4), lrelu(x,0.2) input
__global__ __launch_bounds__(256) void k_upsample(const float* __restrict__ x, const float* __restrict__ w,
                                                  float* __restrict__ h) {
  const int T = 512;
  int b  = blockIdx.x / (LAUD_/T);
  int tb = (blockIdx.x % (LAUD_/T)) * T;
  __shared__ float sx[C_][66];
  for (int idx = threadIdx.x; idx < C_*66; idx += 256) {
    int ci = idx / 66, j = idx % 66;
    int s = tb/8 - 1 + j;
    float v = (s >= 0 && s < LMEL_) ? x[(b*C_ + ci)*LMEL_ + s] : 0.f;
    sx[ci][j] = lrelu_(v, 0.2f);
  }
  __syncthreads();
  int co = threadIdx.x & 31, tq = threadIdx.x >> 5;  // tq 0..7
  for (int ii8 = 0; ii8 < 8; ii8++) {
    int r = (ii8 + 4) & 7;
    int jbase = tq*8 + ((ii8 + 4) >> 3);
    float acc[8];
#pragma unroll
    for (int m = 0; m < 8; m++) acc[m] = 0.f;
    for (int ci = 0; ci < C_; ci++) {
      float wa = w[(ci*C_ + co)*16 + r];
      float wb = w[(ci*C_ + co)*16 + r + 8];
#pragma unroll
      for (int m = 0; m < 8; m++)
        acc[m] = fmaf(wa, sx[ci][jbase + m + 1], fmaf(wb, sx[ci][jbase + m], acc[m]));
    }
#pragma unroll
    for (int m = 0; m < 8; m++)
      h[(b*C_ + co)*LAUD_ + tb + tq*64 + ii8 + 8*m] = acc[m];
  }
}

// ---------------------------------------------------------------- weight transpose for k_lvc: wt[((r*3+kk)*192+j)*64+co] = kw[((r*64+co)*3+kk)*192+j]
__global__ void k_transpose(const float* __restrict__ kw, float* __restrict__ wt) {
  int idx = blockIdx.x*256 + threadIdx.x;
  const int N = KCH_ * HID_ * KPK_;  // 4,718,592
  if (idx >= N) return;
  int co = idx & 63;
  int j  = (idx >> 6) % 192;
  int rk = idx / (64*192);
  int kk = rk % 3;
  int r  = rk / 3;
  wt[idx] = kw[((r*64 + co)*3 + kk)*192 + j];
}

// ---------------------------------------------------------------- K6: dilated conv (32->32, k=3) on lrelu(h+ad,0.2), out lrelu 0.2
template<int DIL>
__global__ __launch_bounds__(256) void k_dilconv(const float* __restrict__ h, const float* __restrict__ ad,
                                                 const float* __restrict__ w, float* __restrict__ y2) {
  const int T = 256;
  int b  = blockIdx.x / (LAUD_/T);
  int tb = (blockIdx.x % (LAUD_/T)) * T;
  __shared__ float ss[C_][T + 2*27 + 2];
  const int W = T + 2*DIL;
  for (int idx = threadIdx.x; idx < C_*W; idx += 256) {
    int ci = idx / W, j = idx % W;
    int t = tb - DIL + j;
    float v = 0.f;
    if (t >= 0 && t < LAUD_) {
      int g = (b*C_ + ci)*LAUD_ + t;
      v = h[g] + ad[g];
    }
    ss[ci][j] = lrelu_(v, 0.2f);
  }
  __syncthreads();
  int co = threadIdx.x & 31, tq = threadIdx.x >> 5;
  float acc[32];
#pragma unroll
  for (int ii = 0; ii < 32; ii++) acc[ii] = 0.f;
  const float* wr = w + co*C_*3;
  for (int ci = 0; ci < C_; ci++) {
    float w0 = wr[ci*3], w1 = wr[ci*3+1], w2 = wr[ci*3+2];
#pragma unroll
    for (int ii = 0; ii < 32; ii++) {
      int tl = tq*32 + ii;
      acc[ii] = fmaf(w0, ss[ci][tl], fmaf(w1, ss[ci][tl + DIL], fmaf(w2, ss[ci][tl + 2*DIL], acc[ii])));
    }
  }
  float* op = y2 + (b*C_ + co)*LAUD_ + tb + tq*32;
#pragma unroll
  for (int ii = 0; ii < 32; ii++) op[ii] = lrelu_(acc[ii], 0.2f);
}

// ---------------------------------------------------------------- K7: fused kernel-prediction GEMM + LVC + gate + h update
#define NL7 32
#define FPT 4
__global__ __launch_bounds__(512) void k_lvc(const float* __restrict__ hkp, const float* __restrict__ wt,
                                             const float* __restrict__ kb, const float* __restrict__ biasb,
                                             const float* __restrict__ y2, const float* __restrict__ ad,
                                             float* __restrict__ h, int layer) {
  int b  = blockIdx.x / (LMEL_/NL7);
  int lb = (blockIdx.x % (LMEL_/NL7)) * NL7;
  __shared__ __align__(16) float sh[HID_][NL7 + 4];        // 34 used, 36 stride
  __shared__ __align__(16) float sy[C_][NL7*HOP_ + 4];     // 258 used, 260 stride
  for (int idx = threadIdx.x; idx < HID_*(NL7+2); idx += 512) {
    int hh = idx / (NL7+2), j = idx % (NL7+2);
    int l = lb - 1 + j;
    sh[hh][j] = (l >= 0 && l < LMEL_) ? hkp[(b*HID_ + hh)*LMEL_ + l] : 0.f;
  }
  for (int idx = threadIdx.x; idx < C_*(NL7*HOP_+2); idx += 512) {
    int ci = idx / (NL7*HOP_+2), j = idx % (NL7*HOP_+2);
    int t = lb*HOP_ - 1 + j;
    sy[ci][j] = (t >= 0 && t < LAUD_) ? y2[(b*C_ + ci)*LAUD_ + t] : 0.f;
  }
  __syncthreads();

  int co = threadIdx.x & 63;
  int fq = threadIdx.x >> 6;   // 0..7
  int f0 = fq * FPT;

  float oacc[FPT][HOP_];
#pragma unroll
  for (int f = 0; f < FPT; f++) {
    float bv = biasb[(b*BCH_ + layer*2*C_ + co)*LMEL_ + lb + f0 + f];
#pragma unroll
    for (int s = 0; s < HOP_; s++) oacc[f][s] = bv;
  }

  const float* wtb = wt + (size_t)(layer*C_*KPK_)*(HID_*KPK_)*64 + co;
  const int rb = layer*C_*HID_*KPK_ + co*3;   // kb row base: layer*6144 + co*3

  for (int ci = 0; ci < C_; ci++) {
    float syr[FPT][12];
#pragma unroll
    for (int f = 0; f < FPT; f++) {
      float4 a = *reinterpret_cast<const float4*>(&sy[ci][(f0+f)*8]);
      float4 bq = *reinterpret_cast<const float4*>(&sy[ci][(f0+f)*8 + 4]);
      float4 cq = *reinterpret_cast<const float4*>(&sy[ci][(f0+f)*8 + 8]);
      syr[f][0]=a.x; syr[f][1]=a.y; syr[f][2]=a.z; syr[f][3]=a.w;
      syr[f][4]=bq.x; syr[f][5]=bq.y; syr[f][6]=bq.z; syr[f][7]=bq.w;
      syr[f][8]=cq.x; syr[f][9]=cq.y; syr[f][10]=cq.z; syr[f][11]=cq.w;
    }
#pragma unroll
    for (int kk = 0; kk < KPK_; kk++) {
      const float* wp = wtb + (size_t)((ci*3 + kk)*192)*64;
      float kbv = kb[rb + ci*192 + kk];
      float kern[FPT];
#pragma unroll
      for (int f = 0; f < FPT; f++) kern[f] = kbv;
      for (int hh = 0; hh < HID_; hh++) {
        float4 h4 = *reinterpret_cast<const float4*>(&sh[hh][f0]);
        float2 h2 = *reinterpret_cast<const float2*>(&sh[hh][f0 + 4]);
        float hv[6] = {h4.x, h4.y, h4.z, h4.w, h2.x, h2.y};
#pragma unroll
        for (int q = 0; q < 3; q++) {
          float wv = wp[(hh*3 + q)*64];
#pragma unroll
          for (int f = 0; f < FPT; f++) kern[f] = fmaf(wv, hv[f + q], kern[f]);
        }
      }
#pragma unroll
      for (int f = 0; f < FPT; f++)
#pragma unroll
        for (int s = 0; s < HOP_; s++)
          oacc[f][s] = fmaf(kern[f], syr[f][s + kk], oacc[f][s]);
    }
  }

  // gate epilogue: partner lane co^32 holds the tanh half
#pragma unroll
  for (int f = 0; f < FPT; f++) {
#pragma unroll
    for (int s = 0; s < HOP_; s++) {
      float v = oacc[f][s];
      float other = __shfl_xor(v, 32);
      if (co < 32) {
        float g = (1.f / (1.f + __expf(-v))) * tanhf(other);
        int t = (lb + f0 + f)*HOP_ + s;
        int idx = (b*C_ + co)*LAUD_ + t;
        h[idx] = h[idx] + ad[idx] + g;
      }
    }
  }
}

// ---------------------------------------------------------------- launcher
extern "C" void kernel_launch(void* const* d_in, const int* in_sizes, int n_in,
                              void* d_out, int out_size, void* d_ws, size_t ws_size,
                              hipStream_t stream) {
  const float* x     = (const float*)d_in[0];
  const float* ad    = (const float*)d_in[1];
  const float* c     = (const float*)d_in[2];
  const float* ne    = (const float*)d_in[3];
  const float* fw    = (const float*)d_in[4];
  const float* fb    = (const float*)d_in[5];
  const float* upw   = (const float*)d_in[6];
  const float* convw = (const float*)d_in[7];
  const float* kinw  = (const float*)d_in[8];
  const float* kinb  = (const float*)d_in[9];
  const float* krw1  = (const float*)d_in[10];
  const float* krb1  = (const float*)d_in[11];
  const float* krw2  = (const float*)d_in[12];
  const float* krb2  = (const float*)d_in[13];
  const float* kkw   = (const float*)d_in[14];
  const float* kkb   = (const float*)d_in[15];
  const float* kbw   = (const float*)d_in[16];
  const float* kbb   = (const float*)d_in[17];
  float* h = (float*)d_out;

  float* ws = (float*)d_ws;
  float* cond  = ws; ws += B_*COND_*LMEL_;
  float* hkpa  = ws; ws += B_*HID_*LMEL_;
  float* hkpb  = ws; ws += B_*HID_*LMEL_;
  float* biasb = ws; ws += B_*BCH_*LMEL_;
  float* y2    = ws; ws += B_*C_*LAUD_;
  float* wt    = ws; ws += KCH_*HID_*KPK_;

  k_transpose<<<(KCH_*HID_*KPK_ + 255)/256, 256, 0, stream>>>(kkw, wt);
  k_noise_cond<<<B_*COND_, 256, 0, stream>>>(ne, fw, fb, c, cond);
  k_kp_in<<<B_*(LMEL_/64), 256, 0, stream>>>(cond, kinw, kinb, hkpa);
  for (int i = 0; i < 3; i++) {
    k_kp_res<<<B_*(LMEL_/64), 256, 0, stream>>>(hkpa, krw1 + i*HID_*HID_*3, krb1 + i*HID_, nullptr, hkpb);
    k_kp_res<<<B_*(LMEL_/64), 256, 0, stream>>>(hkpb, krw2 + i*HID_*HID_*3, krb2 + i*HID_, hkpa, hkpa);
  }
  k_kp_bias<<<B_*(LMEL_/32), 256, 0, stream>>>(hkpa, kbw, kbb, biasb);
  k_upsample<<<B_*(LAUD_/512), 256, 0, stream>>>(x, upw, h);

  for (int i = 0; i < LAYERS_; i++) {
    const float* wci = convw + i*C_*C_*3;
    switch (i) {
      case 0: k_dilconv<1 ><<<B_*(LAUD_/256), 256, 0, stream>>>(h, ad, wci, y2); break;
      case 1: k_dilconv<3 ><<<B_*(LAUD_/256), 256, 0, stream>>>(h, ad, wci, y2); break;
      case 2: k_dilconv<9 ><<<B_*(LAUD_/256), 256, 0, stream>>>(h, ad, wci, y2); break;
      case 3: k_dilconv<27><<<B_*(LAUD_/256), 256, 0, stream>>>(h, ad, wci, y2); break;
    }
    k_lvc<<<B_*(LMEL_/NL7), 512, 0, stream>>>(hkpa, wt, kkb, biasb, y2, ad, h, i);
  }
}

// Round 2
// 599.322 us; speedup vs baseline: 11.6886x; 11.6886x over previous
//
#include <hip/hip_runtime.h>
#include <math.h>

#define B_      4
#define C_      32
#define COND_   80
#define LMEL_   2048
#define HOP_    8
#define UP_     8
#define LAYERS_ 4
#define K_      3
#define HID_    64
#define KPK_    3
#define EMB_    512
#define LAUD_   (LMEL_*UP_)          // 16384
#define KCH_    (LAYERS_*C_*2*C_*K_) // 24576
#define BCH_    (LAYERS_*2*C_)       // 256

typedef short v8s __attribute__((ext_vector_type(8)));
typedef float v4f __attribute__((ext_vector_type(4)));

__device__ __forceinline__ float lrelu_(float v, float s) { return v >= 0.f ? v : s * v; }

__device__ __forceinline__ unsigned short f2bf(float f) {  // RNE float->bf16
  unsigned int x = __float_as_uint(f);
  unsigned int r = (x + 0x7FFFu + ((x >> 16) & 1u)) >> 16;
  return (unsigned short)r;
}

// ---------------------------------------------------------------- K1: noise + condition
__global__ void k_noise_cond(const float* __restrict__ ne, const float* __restrict__ fw,
                             const float* __restrict__ fb, const float* __restrict__ c,
                             float* __restrict__ cond) {
  int b = blockIdx.x / COND_;
  int cc = blockIdx.x % COND_;
  __shared__ float red[256];
  float p = 0.f;
  for (int j = threadIdx.x; j < EMB_; j += 256)
    p += ne[b*EMB_ + j] * fw[cc*EMB_ + j];
  red[threadIdx.x] = p;
  __syncthreads();
  for (int s = 128; s > 0; s >>= 1) {
    if (threadIdx.x < s) red[threadIdx.x] += red[threadIdx.x + s];
    __syncthreads();
  }
  float noise = red[0] + fb[cc];
  const float* cp = c + (b*COND_ + cc)*LMEL_;
  float* op = cond + (b*COND_ + cc)*LMEL_;
  for (int l = threadIdx.x; l < LMEL_; l += 256) op[l] = cp[l] + noise;
}

// ---------------------------------------------------------------- K2: KP input conv (80->64, k=5, pad=2, lrelu 0.1)
__global__ __launch_bounds__(256) void k_kp_in(const float* __restrict__ cond, const float* __restrict__ w,
                                               const float* __restrict__ bias, float* __restrict__ out) {
  const int T = 64;
  int b  = blockIdx.x / (LMEL_/T);
  int lb = (blockIdx.x % (LMEL_/T)) * T;
  __shared__ float sc[COND_][T + 4];
  for (int idx = threadIdx.x; idx < COND_*(T+4); idx += 256) {
    int cc = idx / (T+4), j = idx % (T+4);
    int l = lb + j - 2;
    sc[cc][j] = (l >= 0 && l < LMEL_) ? cond[(b*COND_ + cc)*LMEL_ + l] : 0.f;
  }
  __syncthreads();
  int ch = threadIdx.x & 63;
  int lq = threadIdx.x >> 6;  // 0..3, 16 l's each
  float acc[16];
#pragma unroll
  for (int ii = 0; ii < 16; ii++) acc[ii] = bias[ch];
  const float* wr = w + ch*COND_*5;
  for (int cc = 0; cc < COND_; cc++) {
    float r[20];
#pragma unroll
    for (int j = 0; j < 20; j++) r[j] = sc[cc][lq*16 + j];
#pragma unroll
    for (int k = 0; k < 5; k++) {
      float wv = wr[cc*5 + k];
#pragma unroll
      for (int ii = 0; ii < 16; ii++) acc[ii] = fmaf(wv, r[ii + k], acc[ii]);
    }
  }
  float* op = out + (b*HID_ + ch)*LMEL_ + lb + lq*16;
#pragma unroll
  for (int ii = 0; ii < 16; ii++) op[ii] = lrelu_(acc[ii], 0.1f);
}

// ---------------------------------------------------------------- K3: KP res conv (64->64, k=3, pad=1, lrelu 0.1, opt residual)
__global__ __launch_bounds__(256) void k_kp_res(const float* __restrict__ in, const float* __restrict__ w,
                                                const float* __restrict__ bias, const float* __restrict__ res,
                                                float* __restrict__ out) {
  const int T = 64;
  int b  = blockIdx.x / (LMEL_/T);
  int lb = (blockIdx.x % (LMEL_/T)) * T;
  __shared__ float si[HID_][T + 2];
  for (int idx = threadIdx.x; idx < HID_*(T+2); idx += 256) {
    int cc = idx / (T+2), j = idx % (T+2);
    int l = lb + j - 1;
    si[cc][j] = (l >= 0 && l < LMEL_) ? in[(b*HID_ + cc)*LMEL_ + l] : 0.f;
  }
  __syncthreads();
  int ch = threadIdx.x & 63;
  int lq = threadIdx.x >> 6;
  float acc[16];
#pragma unroll
  for (int ii = 0; ii < 16; ii++) acc[ii] = bias[ch];
  const float* wr = w + ch*HID_*3;
  for (int cc = 0; cc < HID_; cc++) {
    float r[18];
#pragma unroll
    for (int j = 0; j < 18; j++) r[j] = si[cc][lq*16 + j];
#pragma unroll
    for (int k = 0; k < 3; k++) {
      float wv = wr[cc*3 + k];
#pragma unroll
      for (int ii = 0; ii < 16; ii++) acc[ii] = fmaf(wv, r[ii + k], acc[ii]);
    }
  }
  int lo = lb + lq*16;
  float* op = out + (b*HID_ + ch)*LMEL_ + lo;
  const float* rp = res ? res + (b*HID_ + ch)*LMEL_ + lo : nullptr;
#pragma unroll
  for (int ii = 0; ii < 16; ii++) {
    float v = lrelu_(acc[ii], 0.1f);
    if (rp) v += rp[ii];
    op[ii] = v;
  }
}

// ---------------------------------------------------------------- K4: bias conv (64->256, k=3, pad=1)
__global__ __launch_bounds__(256) void k_kp_bias(const float* __restrict__ in, const float* __restrict__ w,
                                                 const float* __restrict__ bias, float* __restrict__ out) {
  const int T = 32;
  int b  = blockIdx.x / (LMEL_/T);
  int lb = (blockIdx.x % (LMEL_/T)) * T;
  __shared__ float si[HID_][T + 2];
  for (int idx = threadIdx.x; idx < HID_*(T+2); idx += 256) {
    int cc = idx / (T+2), j = idx % (T+2);
    int l = lb + j - 1;
    si[cc][j] = (l >= 0 && l < LMEL_) ? in[(b*HID_ + cc)*LMEL_ + l] : 0.f;
  }
  __syncthreads();
  int ch = threadIdx.x;  // 0..255
  float acc[T];
  float bv = bias[ch];
#pragma unroll
  for (int ii = 0; ii < T; ii++) acc[ii] = bv;
  const float* wr = w + ch*HID_*3;
  for (int cc = 0; cc < HID_; cc++) {
    float w0 = wr[cc*3], w1 = wr[cc*3+1], w2 = wr[cc*3+2];
#pragma unroll
    for (int ii = 0; ii < T; ii++)
      acc[ii] = fmaf(w0, si[cc][ii], fmaf(w1, si[cc][ii+1], fmaf(w2, si[cc][ii+2], acc[ii])));
  }
  float* op = out + (b*BCH_ + ch)*LMEL_ + lb;
#pragma unroll
  for (int ii = 0; ii < T; ii++) op[ii] = acc[ii];
}

// ---------------------------------------------------------------- K5: upsample (conv_transpose1d stride 8, k=16, pad=4), lrelu(x,0.2) input
__global__ __launch_bounds__(256) void k_upsample(const float* __restrict__ x, const float* __restrict__ w,
                                                  float* __restrict__ h) {
  const int T = 512;
  int b  = blockIdx.x / (LAUD_/T);
  int tb = (blockIdx.x % (LAUD_/T)) * T;
  __shared__ float sx[C_][66];
  for (int idx = threadIdx.x; idx < C_*66; idx += 256) {
    int ci = idx / 66, j = idx % 66;
    int s = tb/8 - 1 + j;
    float v = (s >= 0 && s < LMEL_) ? x[(b*C_ + ci)*LMEL_ + s] : 0.f;
    sx[ci][j] = lrelu_(v, 0.2f);
  }
  __syncthreads();
  int co = threadIdx.x & 31, tq = threadIdx.x >> 5;  // tq 0..7
  for (int ii8 = 0; ii8 < 8; ii8++) {
    int r = (ii8 + 4) & 7;
    int jbase = tq*8 + ((ii8 + 4) >> 3);
    float acc[8];
#pragma unroll
    for (int m = 0; m < 8; m++) acc[m] = 0.f;
    for (int ci = 0; ci < C_; ci++) {
      float wa = w[(ci*C_ + co)*16 + r];
      float wb = w[(ci*C_ + co)*16 + r + 8];
#pragma unroll
      for (int m = 0; m < 8; m++)
        acc[m] = fmaf(wa, sx[ci][jbase + m + 1], fmaf(wb, sx[ci][jbase + m], acc[m]));
    }
#pragma unroll
    for (int m = 0; m < 8; m++)
      h[(b*C_ + co)*LAUD_ + tb + tq*64 + ii8 + 8*m] = acc[m];
  }
}

// ---------------------------------------------------------------- prep: A-fragment-ordered bf16 weights
// waf flat idx = ((rk*4 + tile)*6 + ks)*512 + lane*8 + i,  rk = layer*96 + ci*3 + kk
// value = kw[row][j], row = ((layer*32+ci)*64 + tile*16 + (lane&15))*3 + kk, j = ks*32 + ((lane>>4)<<3) + i
__global__ void k_mkA(const float* __restrict__ kw, unsigned short* __restrict__ waf) {
  int idx = blockIdx.x*256 + threadIdx.x;
  if (idx >= KCH_*HID_*KPK_) return;   // 4,718,592
  int i    = idx & 7;
  int lane = (idx >> 3) & 63;
  int ks   = (idx >> 9) % 6;
  int tile = (idx / 3072) & 3;
  int rk   = idx / 12288;              // 0..383
  int layer = rk / 96, rem = rk % 96, ci = rem / 3, kk = rem % 3;
  int cout = tile*16 + (lane & 15);
  int j    = ks*32 + ((lane >> 4) << 3) + i;
  int row  = ((layer*32 + ci)*64 + cout)*3 + kk;
  waf[idx] = f2bf(kw[row*192 + j]);
}

// ---------------------------------------------------------------- prep: kernel-conv bias reordered: kbt[(rk*4+tile)*16 + cr]
__global__ void k_mkKbT(const float* __restrict__ kb, float* __restrict__ kbt) {
  int idx = blockIdx.x*256 + threadIdx.x;
  if (idx >= KCH_) return;             // 24576
  int cr = idx & 15, tile = (idx >> 4) & 3, rk = idx >> 6;
  int layer = rk / 96, rem = rk % 96, ci = rem / 3, kk = rem % 3;
  int cout = tile*16 + cr;
  kbt[idx] = kb[((layer*32 + ci)*64 + cout)*3 + kk];
}

// ---------------------------------------------------------------- K6: dilated conv (32->32, k=3) on lrelu(h+ad,0.2), out lrelu 0.2
template<int DIL>
__global__ __launch_bounds__(256) void k_dilconv(const float* __restrict__ h, const float* __restrict__ ad,
                                                 const float* __restrict__ w, float* __restrict__ y2) {
  const int T = 256;
  int b  = blockIdx.x / (LAUD_/T);
  int tb = (blockIdx.x % (LAUD_/T)) * T;
  __shared__ float ss[C_][T + 2*27 + 2];
  const int W = T + 2*DIL;
  for (int idx = threadIdx.x; idx < C_*W; idx += 256) {
    int ci = idx / W, j = idx % W;
    int t = tb - DIL + j;
    float v = 0.f;
    if (t >= 0 && t < LAUD_) {
      int g = (b*C_ + ci)*LAUD_ + t;
      v = h[g] + ad[g];
    }
    ss[ci][j] = lrelu_(v, 0.2f);
  }
  __syncthreads();
  int co = threadIdx.x & 31, tq = threadIdx.x >> 5;
  float acc[32];
#pragma unroll
  for (int ii = 0; ii < 32; ii++) acc[ii] = 0.f;
  const float* wr = w + co*C_*3;
  for (int ci = 0; ci < C_; ci++) {
    float w0 = wr[ci*3], w1 = wr[ci*3+1], w2 = wr[ci*3+2];
#pragma unroll
    for (int ii = 0; ii < 32; ii++) {
      int tl = tq*32 + ii;
      acc[ii] = fmaf(w0, ss[ci][tl], fmaf(w1, ss[ci][tl + DIL], fmaf(w2, ss[ci][tl + 2*DIL], acc[ii])));
    }
  }
  float* op = y2 + (b*C_ + co)*LAUD_ + tb + tq*32;
#pragma unroll
  for (int ii = 0; ii < 32; ii++) op[ii] = lrelu_(acc[ii], 0.2f);
}

// ---------------------------------------------------------------- K7: MFMA-fused kernel-prediction GEMM + LVC + gate + h update
// block = (b, 16 frames). 8 waves: wave w -> cout-tile (w&3), ci-half (w>>2).
// MFMA 16x16x32 bf16: D[row=cout_rel][col=frame]; A row = lane&15, k = 8*(lane>>4)+i;
// B: k = 8*(lane>>4)+i, col = lane&15; C/D: col = lane&15, row = (lane>>4)*4 + reg.
#define FR_ 16
__global__ __launch_bounds__(512, 4) void k_lvc_mfma(
    const float* __restrict__ hkp, const unsigned short* __restrict__ waf,
    const float* __restrict__ kbt, const float* __restrict__ biasb,
    const float* __restrict__ y2, const float* __restrict__ ad,
    float* __restrict__ h, int layer) {
  int b  = blockIdx.x >> 7;               // 128 frame-tiles of 16
  int l0 = (blockIdx.x & 127) * FR_;

  __shared__ __align__(16) float sy[C_][FR_*HOP_ + 4];   // 132 stride, 130 used
  __shared__ __align__(16) float shh[HID_][20];          // 18 used
  __shared__ __align__(16) unsigned short FB[6*64*8];    // B fragments, 6 ksteps
  __shared__ float red[4][64][33];                       // stride 33: conflict-free

  int tid = threadIdx.x;
  // stage y2 window
  for (int idx = tid; idx < C_*(FR_*HOP_+2); idx += 512) {
    int ci = idx / (FR_*HOP_+2), j = idx % (FR_*HOP_+2);
    int t = l0*HOP_ - 1 + j;
    sy[ci][j] = (t >= 0 && t < LAUD_) ? y2[(b*C_ + ci)*LAUD_ + t] : 0.f;
  }
  // stage hkp window
  for (int idx = tid; idx < HID_*18; idx += 512) {
    int hh = idx / 18, j = idx % 18;
    int l = l0 - 1 + j;
    shh[hh][j] = (l >= 0 && l < LMEL_) ? hkp[(b*HID_ + hh)*LMEL_ + l] : 0.f;
  }
  __syncthreads();
  // build B fragments in fragment order
  for (int idx = tid; idx < 3072; idx += 512) {
    int i = idx & 7, lane2 = (idx >> 3) & 63, ks = idx >> 9;
    int j = ks*32 + ((lane2 >> 4) << 3) + i;
    int f2 = lane2 & 15;
    int hh = j / 3, q = j - hh*3;
    FB[idx] = f2bf(shh[hh][f2 + q]);
  }
  __syncthreads();

  int wave = tid >> 6, lane = tid & 63;
  int tile = wave & 3, cihalf = wave >> 2;
  int f = lane & 15;

  // hoist B fragments to registers (shared across all 48 tiles of this wave)
  v8s bfr[6];
#pragma unroll
  for (int ks = 0; ks < 6; ks++)
    bfr[ks] = *reinterpret_cast<const v8s*>(&FB[(ks*64 + lane)*8]);

  float o[4][8];
#pragma unroll
  for (int r = 0; r < 4; r++)
#pragma unroll
    for (int s = 0; s < 8; s++) o[r][s] = 0.f;

  const int rk0 = layer*96 + cihalf*48;   // first rk for this wave's ci-half
  const unsigned short* wbase = waf + ((size_t)rk0*4 + tile)*3072 + lane*8;
  const float* kbbase = kbt + (rk0*4 + tile)*16 + ((lane >> 4) << 2);

  for (int ci16 = 0; ci16 < 16; ci16++) {
    int ci = cihalf*16 + ci16;
    float syr[12];
    {
      float4 s0 = *reinterpret_cast<const float4*>(&sy[ci][f*8]);
      float4 s1 = *reinterpret_cast<const float4*>(&sy[ci][f*8 + 4]);
      float4 s2 = *reinterpret_cast<const float4*>(&sy[ci][f*8 + 8]);
      syr[0]=s0.x; syr[1]=s0.y; syr[2]=s0.z; syr[3]=s0.w;
      syr[4]=s1.x; syr[5]=s1.y; syr[6]=s1.z; syr[7]=s1.w;
      syr[8]=s2.x; syr[9]=s2.y; syr[10]=s2.z; syr[11]=s2.w;
    }
#pragma unroll
    for (int kk = 0; kk < 3; kk++) {
      const unsigned short* wp = wbase + (size_t)(ci16*3 + kk)*12288;
      v4f acc = {0.f, 0.f, 0.f, 0.f};
#pragma unroll
      for (int ks = 0; ks < 6; ks++) {
        v8s a = *reinterpret_cast<const v8s*>(wp + ks*512);
        acc = __builtin_amdgcn_mfma_f32_16x16x32_bf16(a, bfr[ks], acc, 0, 0, 0);
      }
      float4 kb4 = *reinterpret_cast<const float4*>(kbbase + (ci16*3 + kk)*64);
#pragma unroll
      for (int r = 0; r < 4; r++) {
        float kern = acc[r] + ((const float*)&kb4)[r];
#pragma unroll
        for (int s = 0; s < 8; s++)
          o[r][s] = fmaf(kern, syr[kk + s], o[r][s]);
      }
    }
  }

  // cross-ci-half reduction + gate
  if (wave >= 4) {
#pragma unroll
    for (int r = 0; r < 4; r++)
#pragma unroll
      for (int s = 0; s < 8; s++) red[tile][lane][r*8 + s] = o[r][s];
  }
  __syncthreads();
  if (wave < 4) {
#pragma unroll
    for (int r = 0; r < 4; r++) {
      int cout = tile*16 + ((lane >> 4) << 2) + r;
      float bv = biasb[((size_t)b*BCH_ + layer*2*C_ + cout)*LMEL_ + l0 + f];
#pragma unroll
      for (int s = 0; s < 8; s++)
        o[r][s] += red[tile][lane][r*8 + s] + bv;
    }
    if (wave >= 2) {  // tanh half: publish full sums
#pragma unroll
      for (int r = 0; r < 4; r++)
#pragma unroll
        for (int s = 0; s < 8; s++) red[tile][lane][r*8 + s] = o[r][s];
    }
  }
  __syncthreads();
  if (wave < 2) {
#pragma unroll
    for (int r = 0; r < 4; r++) {
      int cout = tile*16 + ((lane >> 4) << 2) + r;   // 0..31
      size_t base = ((size_t)b*C_ + cout)*LAUD_ + (size_t)(l0 + f)*HOP_;
      float4 h0 = *reinterpret_cast<const float4*>(&h[base]);
      float4 h1 = *reinterpret_cast<const float4*>(&h[base + 4]);
      float4 a0 = *reinterpret_cast<const float4*>(&ad[base]);
      float4 a1 = *reinterpret_cast<const float4*>(&ad[base + 4]);
      float out[8];
#pragma unroll
      for (int s = 0; s < 8; s++) {
        float v  = o[r][s];
        float tv = red[tile + 2][lane][r*8 + s];
        float sig = 1.f / (1.f + __expf(-v));
        float th  = 1.f - 2.f / (1.f + __expf(2.f*tv));
        float hv = (s < 4) ? ((const float*)&h0)[s] : ((const float*)&h1)[s-4];
        float av = (s < 4) ? ((const float*)&a0)[s] : ((const float*)&a1)[s-4];
        out[s] = hv + av + sig * th;
      }
      *reinterpret_cast<float4*>(&h[base])     = make_float4(out[0], out[1], out[2], out[3]);
      *reinterpret_cast<float4*>(&h[base + 4]) = make_float4(out[4], out[5], out[6], out[7]);
    }
  }
}

// ---------------------------------------------------------------- launcher
extern "C" void kernel_launch(void* const* d_in, const int* in_sizes, int n_in,
                              void* d_out, int out_size, void* d_ws, size_t ws_size,
                              hipStream_t stream) {
  const float* x     = (const float*)d_in[0];
  const float* ad    = (const float*)d_in[1];
  const float* c     = (const float*)d_in[2];
  const float* ne    = (const float*)d_in[3];
  const float* fw    = (const float*)d_in[4];
  const float* fb    = (const float*)d_in[5];
  const float* upw   = (const float*)d_in[6];
  const float* convw = (const float*)d_in[7];
  const float* kinw  = (const float*)d_in[8];
  const float* kinb  = (const float*)d_in[9];
  const float* krw1  = (const float*)d_in[10];
  const float* krb1  = (const float*)d_in[11];
  const float* krw2  = (const float*)d_in[12];
  const float* krb2  = (const float*)d_in[13];
  const float* kkw   = (const float*)d_in[14];
  const float* kkb   = (const float*)d_in[15];
  const float* kbw   = (const float*)d_in[16];
  const float* kbb   = (const float*)d_in[17];
  float* h = (float*)d_out;

  float* ws = (float*)d_ws;
  float* cond  = ws; ws += B_*COND_*LMEL_;
  float* hkpa  = ws; ws += B_*HID_*LMEL_;
  float* hkpb  = ws; ws += B_*HID_*LMEL_;
  float* biasb = ws; ws += B_*BCH_*LMEL_;
  float* y2    = ws; ws += B_*C_*LAUD_;
  float* kbt   = ws; ws += KCH_;
  unsigned short* waf = (unsigned short*)ws; ws += (KCH_*HID_*KPK_)/2;

  k_mkA<<<(KCH_*HID_*KPK_ + 255)/256, 256, 0, stream>>>(kkw, waf);
  k_mkKbT<<<(KCH_ + 255)/256, 256, 0, stream>>>(kkb, kbt);
  k_noise_cond<<<B_*COND_, 256, 0, stream>>>(ne, fw, fb, c, cond);
  k_kp_in<<<B_*(LMEL_/64), 256, 0, stream>>>(cond, kinw, kinb, hkpa);
  for (int i = 0; i < 3; i++) {
    k_kp_res<<<B_*(LMEL_/64), 256, 0, stream>>>(hkpa, krw1 + i*HID_*HID_*3, krb1 + i*HID_, nullptr, hkpb);
    k_kp_res<<<B_*(LMEL_/64), 256, 0, stream>>>(hkpb, krw2 + i*HID_*HID_*3, krb2 + i*HID_, hkpa, hkpa);
  }
  k_kp_bias<<<B_*(LMEL_/32), 256, 0, stream>>>(hkpa, kbw, kbb, biasb);
  k_upsample<<<B_*(LAUD_/512), 256, 0, stream>>>(x, upw, h);

  for (int i = 0; i < LAYERS_; i++) {
    const float* wci = convw + i*C_*C_*3;
    switch (i) {
      case 0: k_dilconv<1 ><<<B_*(LAUD_/256), 256, 0, stream>>>(h, ad, wci, y2); break;
      case 1: k_dilconv<3 ><<<B_*(LAUD_/256), 256, 0, stream>>>(h, ad, wci, y2); break;
      case 2: k_dilconv<9 ><<<B_*(LAUD_/256), 256, 0, stream>>>(h, ad, wci, y2); break;
      case 3: k_dilconv<27><<<B_*(LAUD_/256), 256, 0, stream>>>(h, ad, wci, y2); break;
    }
    k_lvc_mfma<<<B_*(LMEL_/FR_), 512, 0, stream>>>(hkpa, waf, kbt, biasb, y2, ad, h, i);
  }
}

// Round 3
// 539.993 us; speedup vs baseline: 12.9728x; 1.1099x over previous
//
#include <hip/hip_runtime.h>
#include <math.h>

#define B_      4
#define C_      32
#define COND_   80
#define LMEL_   2048
#define HOP_    8
#define UP_     8
#define LAYERS_ 4
#define K_      3
#define HID_    64
#define KPK_    3
#define EMB_    512
#define LAUD_   (LMEL_*UP_)          // 16384
#define KCH_    (LAYERS_*C_*2*C_*K_) // 24576
#define BCH_    (LAYERS_*2*C_)       // 256

typedef short v8s __attribute__((ext_vector_type(8)));
typedef float v4f __attribute__((ext_vector_type(4)));

__device__ __forceinline__ float lrelu_(float v, float s) { return v >= 0.f ? v : s * v; }

__device__ __forceinline__ unsigned short f2bf(float f) {  // RNE float->bf16
  unsigned int x = __float_as_uint(f);
  unsigned int r = (x + 0x7FFFu + ((x >> 16) & 1u)) >> 16;
  return (unsigned short)r;
}

// ---------------------------------------------------------------- K1: noise + condition
__global__ void k_noise_cond(const float* __restrict__ ne, const float* __restrict__ fw,
                             const float* __restrict__ fb, const float* __restrict__ c,
                             float* __restrict__ cond) {
  int b = blockIdx.x / COND_;
  int cc = blockIdx.x % COND_;
  __shared__ float red[256];
  float p = 0.f;
  for (int j = threadIdx.x; j < EMB_; j += 256)
    p += ne[b*EMB_ + j] * fw[cc*EMB_ + j];
  red[threadIdx.x] = p;
  __syncthreads();
  for (int s = 128; s > 0; s >>= 1) {
    if (threadIdx.x < s) red[threadIdx.x] += red[threadIdx.x + s];
    __syncthreads();
  }
  float noise = red[0] + fb[cc];
  const float* cp = c + (b*COND_ + cc)*LMEL_;
  float* op = cond + (b*COND_ + cc)*LMEL_;
  for (int l = threadIdx.x; l < LMEL_; l += 256) op[l] = cp[l] + noise;
}

// ---------------------------------------------------------------- K2: KP input conv (80->64, k=5, pad=2, lrelu 0.1), T=32
__global__ __launch_bounds__(256) void k_kp_in(const float* __restrict__ cond, const float* __restrict__ w,
                                               const float* __restrict__ bias, float* __restrict__ out) {
  const int T = 32;
  int b  = blockIdx.x / (LMEL_/T);
  int lb = (blockIdx.x % (LMEL_/T)) * T;
  __shared__ float sc[COND_][T + 4];
  for (int idx = threadIdx.x; idx < COND_*(T+4); idx += 256) {
    int cc = idx / (T+4), j = idx % (T+4);
    int l = lb + j - 2;
    sc[cc][j] = (l >= 0 && l < LMEL_) ? cond[(b*COND_ + cc)*LMEL_ + l] : 0.f;
  }
  __syncthreads();
  int ch = threadIdx.x & 63;
  int lq = threadIdx.x >> 6;  // 0..3, 8 l's each
  float acc[8];
#pragma unroll
  for (int ii = 0; ii < 8; ii++) acc[ii] = bias[ch];
  const float* wr = w + ch*COND_*5;
  for (int cc = 0; cc < COND_; cc++) {
    float r[12];
#pragma unroll
    for (int j = 0; j < 12; j++) r[j] = sc[cc][lq*8 + j];
#pragma unroll
    for (int k = 0; k < 5; k++) {
      float wv = wr[cc*5 + k];
#pragma unroll
      for (int ii = 0; ii < 8; ii++) acc[ii] = fmaf(wv, r[ii + k], acc[ii]);
    }
  }
  float* op = out + (b*HID_ + ch)*LMEL_ + lb + lq*8;
#pragma unroll
  for (int ii = 0; ii < 8; ii++) acc[ii] = lrelu_(acc[ii], 0.1f);
  *reinterpret_cast<float4*>(&op[0]) = make_float4(acc[0], acc[1], acc[2], acc[3]);
  *reinterpret_cast<float4*>(&op[4]) = make_float4(acc[4], acc[5], acc[6], acc[7]);
}

// ---------------------------------------------------------------- K3: KP res conv (64->64, k=3, pad=1, lrelu 0.1, opt residual), T=32
__global__ __launch_bounds__(256) void k_kp_res(const float* __restrict__ in, const float* __restrict__ w,
                                                const float* __restrict__ bias, const float* __restrict__ res,
                                                float* __restrict__ out) {
  const int T = 32;
  int b  = blockIdx.x / (LMEL_/T);
  int lb = (blockIdx.x % (LMEL_/T)) * T;
  __shared__ float si[HID_][T + 4];
  for (int idx = threadIdx.x; idx < HID_*(T+2); idx += 256) {
    int cc = idx / (T+2), j = idx % (T+2);
    int l = lb + j - 1;
    si[cc][j] = (l >= 0 && l < LMEL_) ? in[(b*HID_ + cc)*LMEL_ + l] : 0.f;
  }
  __syncthreads();
  int ch = threadIdx.x & 63;
  int lq = threadIdx.x >> 6;
  float acc[8];
#pragma unroll
  for (int ii = 0; ii < 8; ii++) acc[ii] = bias[ch];
  const float* wr = w + ch*HID_*3;
  for (int cc = 0; cc < HID_; cc++) {
    float r[10];
#pragma unroll
    for (int j = 0; j < 10; j++) r[j] = si[cc][lq*8 + j];
#pragma unroll
    for (int k = 0; k < 3; k++) {
      float wv = wr[cc*3 + k];
#pragma unroll
      for (int ii = 0; ii < 8; ii++) acc[ii] = fmaf(wv, r[ii + k], acc[ii]);
    }
  }
  int lo = lb + lq*8;
  float* op = out + (b*HID_ + ch)*LMEL_ + lo;
  const float* rp = res ? res + (b*HID_ + ch)*LMEL_ + lo : nullptr;
#pragma unroll
  for (int ii = 0; ii < 8; ii++) {
    acc[ii] = lrelu_(acc[ii], 0.1f);
    if (rp) acc[ii] += rp[ii];
  }
  *reinterpret_cast<float4*>(&op[0]) = make_float4(acc[0], acc[1], acc[2], acc[3]);
  *reinterpret_cast<float4*>(&op[4]) = make_float4(acc[4], acc[5], acc[6], acc[7]);
}

// ---------------------------------------------------------------- K4: bias conv (64->256, k=3, pad=1), T=16
__global__ __launch_bounds__(256) void k_kp_bias(const float* __restrict__ in, const float* __restrict__ w,
                                                 const float* __restrict__ bias, float* __restrict__ out) {
  const int T = 16;
  int b  = blockIdx.x / (LMEL_/T);
  int lb = (blockIdx.x % (LMEL_/T)) * T;
  __shared__ float si[HID_][T + 2];
  for (int idx = threadIdx.x; idx < HID_*(T+2); idx += 256) {
    int cc = idx / (T+2), j = idx % (T+2);
    int l = lb + j - 1;
    si[cc][j] = (l >= 0 && l < LMEL_) ? in[(b*HID_ + cc)*LMEL_ + l] : 0.f;
  }
  __syncthreads();
  int ch = threadIdx.x;  // 0..255
  float acc[T];
  float bv = bias[ch];
#pragma unroll
  for (int ii = 0; ii < T; ii++) acc[ii] = bv;
  const float* wr = w + ch*HID_*3;
  for (int cc = 0; cc < HID_; cc++) {
    float w0 = wr[cc*3], w1 = wr[cc*3+1], w2 = wr[cc*3+2];
#pragma unroll
    for (int ii = 0; ii < T; ii++)
      acc[ii] = fmaf(w0, si[cc][ii], fmaf(w1, si[cc][ii+1], fmaf(w2, si[cc][ii+2], acc[ii])));
  }
  float* op = out + (b*BCH_ + ch)*LMEL_ + lb;
#pragma unroll
  for (int q = 0; q < 4; q++)
    *reinterpret_cast<float4*>(&op[q*4]) = make_float4(acc[q*4], acc[q*4+1], acc[q*4+2], acc[q*4+3]);
}

// ---------------------------------------------------------------- prep: upsample weight transpose -> wt[(ci*16+j)*32+co]
__global__ void k_mkUp(const float* __restrict__ upw, float* __restrict__ wt) {
  int idx = blockIdx.x*256 + threadIdx.x;
  if (idx >= C_*C_*16) return;
  int co = idx & 31, j = (idx >> 5) & 15, ci = idx >> 9;
  wt[idx] = upw[(ci*C_ + co)*16 + j];
}

// ---------------------------------------------------------------- K5: upsample (conv_transpose1d stride 8, k=16, pad=4), lrelu(x,0.2) input
// out[t] = sum_ci x[s1]*w[ci][co][r] + x[s1-1]*w[ci][co][r+8],  r=(t+4)&7, s1=(t+4)>>3
#define UT 32
__global__ __launch_bounds__(256) void k_upsample(const float* __restrict__ x, const float* __restrict__ wt,
                                                  float* __restrict__ h) {
  int b  = blockIdx.x / 65;
  int s0 = (blockIdx.x % 65) * UT;
  __shared__ float sw[16384];          // [ci][j][co]
  __shared__ float sx[C_][33 + 3];
  for (int idx = threadIdx.x*4; idx < 16384; idx += 1024)
    *reinterpret_cast<float4*>(&sw[idx]) = *reinterpret_cast<const float4*>(&wt[idx]);
  for (int idx = threadIdx.x; idx < C_*33; idx += 256) {
    int ci = idx / 33, i = idx % 33;
    int s = s0 - 1 + i;
    float v = (s >= 0 && s < LMEL_) ? x[(b*C_ + ci)*LMEL_ + s] : 0.f;
    sx[ci][i] = lrelu_(v, 0.2f);
  }
  __syncthreads();
  int co = threadIdx.x & 31, sq = threadIdx.x >> 5;  // sq 0..7, 4 frames each
  float acc[4][8];
#pragma unroll
  for (int k = 0; k < 4; k++)
#pragma unroll
    for (int r = 0; r < 8; r++) acc[k][r] = 0.f;
  for (int ci = 0; ci < C_; ci++) {
    float xv[5];
#pragma unroll
    for (int m = 0; m < 5; m++) xv[m] = sx[ci][sq*4 + m];
    const float* wl = &sw[ci*512 + co];
#pragma unroll
    for (int r = 0; r < 8; r++) {
      float wa = wl[r*32];
      float wb = wl[(r+8)*32];
#pragma unroll
      for (int k = 0; k < 4; k++)
        acc[k][r] = fmaf(wa, xv[k+1], fmaf(wb, xv[k], acc[k][r]));
    }
  }
  float* op = h + ((size_t)b*C_ + co)*LAUD_;
#pragma unroll
  for (int k = 0; k < 4; k++) {
    int s1 = s0 + sq*4 + k;
    int lo = 8*s1 - 4;
    if (lo >= 0 && lo + 4 <= LAUD_)
      *reinterpret_cast<float4*>(&op[lo]) = make_float4(acc[k][0], acc[k][1], acc[k][2], acc[k][3]);
    if (lo >= -4 && lo + 8 <= LAUD_)
      *reinterpret_cast<float4*>(&op[lo+4]) = make_float4(acc[k][4], acc[k][5], acc[k][6], acc[k][7]);
  }
}

// ---------------------------------------------------------------- prep: A-fragment-ordered bf16 weights
__global__ void k_mkA(const float* __restrict__ kw, unsigned short* __restrict__ waf) {
  int idx = blockIdx.x*256 + threadIdx.x;
  if (idx >= KCH_*HID_*KPK_) return;   // 4,718,592
  int i    = idx & 7;
  int lane = (idx >> 3) & 63;
  int ks   = (idx >> 9) % 6;
  int tile = (idx / 3072) & 3;
  int rk   = idx / 12288;              // 0..383
  int layer = rk / 96, rem = rk % 96, ci = rem / 3, kk = rem % 3;
  int cout = tile*16 + (lane & 15);
  int j    = ks*32 + ((lane >> 4) << 3) + i;
  int row  = ((layer*32 + ci)*64 + cout)*3 + kk;
  waf[idx] = f2bf(kw[row*192 + j]);
}

// ---------------------------------------------------------------- prep: kernel-conv bias reordered
__global__ void k_mkKbT(const float* __restrict__ kb, float* __restrict__ kbt) {
  int idx = blockIdx.x*256 + threadIdx.x;
  if (idx >= KCH_) return;             // 24576
  int cr = idx & 15, tile = (idx >> 4) & 3, rk = idx >> 6;
  int layer = rk / 96, rem = rk % 96, ci = rem / 3, kk = rem % 3;
  int cout = tile*16 + cr;
  kbt[idx] = kb[((layer*32 + ci)*64 + cout)*3 + kk];
}

// ---------------------------------------------------------------- K6: dilated conv (32->32, k=3) on lrelu(h+ad,0.2), out lrelu 0.2, T=128
template<int DIL>
__global__ __launch_bounds__(256) void k_dilconv(const float* __restrict__ h, const float* __restrict__ ad,
                                                 const float* __restrict__ w, float* __restrict__ y2) {
  const int T = 128;
  int b  = blockIdx.x / (LAUD_/T);
  int tb = (blockIdx.x % (LAUD_/T)) * T;
  const int W = T + 2*DIL;
  __shared__ float ss[C_][T + 2*27 + 4];
  for (int idx = threadIdx.x; idx < C_*W; idx += 256) {
    int ci = idx / W, j = idx % W;
    int t = tb - DIL + j;
    float v = 0.f;
    if (t >= 0 && t < LAUD_) {
      int g = (b*C_ + ci)*LAUD_ + t;
      v = h[g] + ad[g];
    }
    ss[ci][j] = lrelu_(v, 0.2f);
  }
  __syncthreads();
  int co = threadIdx.x & 31, tq = threadIdx.x >> 5;
  float acc[16];
#pragma unroll
  for (int ii = 0; ii < 16; ii++) acc[ii] = 0.f;
  const float* wr = w + co*C_*3;
  for (int ci = 0; ci < C_; ci++) {
    float w0 = wr[ci*3], w1 = wr[ci*3+1], w2 = wr[ci*3+2];
#pragma unroll
    for (int ii = 0; ii < 16; ii++) {
      int tl = tq*16 + ii;
      acc[ii] = fmaf(w0, ss[ci][tl], fmaf(w1, ss[ci][tl + DIL], fmaf(w2, ss[ci][tl + 2*DIL], acc[ii])));
    }
  }
  float* op = y2 + (b*C_ + co)*LAUD_ + tb + tq*16;
#pragma unroll
  for (int ii = 0; ii < 16; ii++) acc[ii] = lrelu_(acc[ii], 0.2f);
#pragma unroll
  for (int q = 0; q < 4; q++)
    *reinterpret_cast<float4*>(&op[q*4]) = make_float4(acc[q*4], acc[q*4+1], acc[q*4+2], acc[q*4+3]);
}

// ---------------------------------------------------------------- K7: MFMA-fused KP-GEMM + LVC + gate + h update, FPW=2 (32 frames/block)
#define FR2 32
__global__ __launch_bounds__(512, 2) void k_lvc_mfma(
    const float* __restrict__ hkp, const unsigned short* __restrict__ waf,
    const float* __restrict__ kbt, const float* __restrict__ biasb,
    const float* __restrict__ y2, const float* __restrict__ ad,
    float* __restrict__ h, int layer) {
  int b  = blockIdx.x >> 6;               // 64 frame-tiles of 32
  int l0 = (blockIdx.x & 63) * FR2;

  __shared__ __align__(16) float sy[C_][FR2*HOP_ + 4];     // 260 stride, 258 used
  __shared__ __align__(16) float shh[HID_][36];            // 34 used
  __shared__ __align__(16) unsigned short FB[2*6*64*8];    // B frags, 2 tiles x 6 ksteps
  __shared__ float red[4][64][33];

  int tid = threadIdx.x;
  for (int idx = tid; idx < C_*(FR2*HOP_+2); idx += 512) {
    int ci = idx / (FR2*HOP_+2), j = idx % (FR2*HOP_+2);
    int t = l0*HOP_ - 1 + j;
    sy[ci][j] = (t >= 0 && t < LAUD_) ? y2[(b*C_ + ci)*LAUD_ + t] : 0.f;
  }
  for (int idx = tid; idx < HID_*34; idx += 512) {
    int hh = idx / 34, j = idx % 34;
    int l = l0 - 1 + j;
    shh[hh][j] = (l >= 0 && l < LMEL_) ? hkp[(b*HID_ + hh)*LMEL_ + l] : 0.f;
  }
  __syncthreads();
  // build B fragments for both 16-frame sub-tiles
  for (int idx = tid; idx < 6144; idx += 512) {
    int i = idx & 7, lane2 = (idx >> 3) & 63, gk = idx >> 9;  // gk = g*6+ks
    int ks = gk % 6, g = gk / 6;
    int k = ks*32 + ((lane2 >> 4) << 3) + i;
    int col = lane2 & 15;
    int hh = k / 3, q = k - hh*3;
    FB[idx] = f2bf(shh[hh][g*16 + col + q]);
  }
  __syncthreads();

  int wave = tid >> 6, lane = tid & 63;
  int tile = wave & 3, cihalf = wave >> 2;
  int f = lane & 15;

  v8s bfrA[6], bfrB[6];
#pragma unroll
  for (int ks = 0; ks < 6; ks++) {
    bfrA[ks] = *reinterpret_cast<const v8s*>(&FB[(ks*64 + lane)*8]);
    bfrB[ks] = *reinterpret_cast<const v8s*>(&FB[((6 + ks)*64 + lane)*8]);
  }

  float o[2][4][8];
#pragma unroll
  for (int g = 0; g < 2; g++)
#pragma unroll
    for (int r = 0; r < 4; r++)
#pragma unroll
      for (int s = 0; s < 8; s++) o[g][r][s] = 0.f;

  const int rk0 = layer*96 + cihalf*48;
  const unsigned short* wbase = waf + ((size_t)rk0*4 + tile)*3072 + lane*8;
  const float* kbbase = kbt + (rk0*4 + tile)*16 + ((lane >> 4) << 2);

  for (int ci16 = 0; ci16 < 16; ci16++) {
    int ci = cihalf*16 + ci16;
    float syr[2][12];
#pragma unroll
    for (int g = 0; g < 2; g++) {
      float4 s0 = *reinterpret_cast<const float4*>(&sy[ci][(g*16 + f)*8]);
      float4 s1 = *reinterpret_cast<const float4*>(&sy[ci][(g*16 + f)*8 + 4]);
      float4 s2 = *reinterpret_cast<const float4*>(&sy[ci][(g*16 + f)*8 + 8]);
      syr[g][0]=s0.x; syr[g][1]=s0.y; syr[g][2]=s0.z; syr[g][3]=s0.w;
      syr[g][4]=s1.x; syr[g][5]=s1.y; syr[g][6]=s1.z; syr[g][7]=s1.w;
      syr[g][8]=s2.x; syr[g][9]=s2.y; syr[g][10]=s2.z; syr[g][11]=s2.w;
    }
#pragma unroll
    for (int kk = 0; kk < 3; kk++) {
      const unsigned short* wp = wbase + (size_t)(ci16*3 + kk)*12288;
      v4f acc0 = {0.f, 0.f, 0.f, 0.f};
      v4f acc1 = {0.f, 0.f, 0.f, 0.f};
#pragma unroll
      for (int ks = 0; ks < 6; ks++) {
        v8s a = *reinterpret_cast<const v8s*>(wp + ks*512);
        acc0 = __builtin_amdgcn_mfma_f32_16x16x32_bf16(a, bfrA[ks], acc0, 0, 0, 0);
        acc1 = __builtin_amdgcn_mfma_f32_16x16x32_bf16(a, bfrB[ks], acc1, 0, 0, 0);
      }
      float4 kb4 = *reinterpret_cast<const float4*>(kbbase + (ci16*3 + kk)*64);
#pragma unroll
      for (int r = 0; r < 4; r++) {
        float k0 = acc0[r] + ((const float*)&kb4)[r];
        float k1 = acc1[r] + ((const float*)&kb4)[r];
#pragma unroll
        for (int s = 0; s < 8; s++) {
          o[0][r][s] = fmaf(k0, syr[0][kk + s], o[0][r][s]);
          o[1][r][s] = fmaf(k1, syr[1][kk + s], o[1][r][s]);
        }
      }
    }
  }

  // epilogue: two passes (one per 16-frame sub-tile), reusing red
#pragma unroll 1
  for (int g = 0; g < 2; g++) {
    if (g) __syncthreads();
    if (wave >= 4) {
#pragma unroll
      for (int r = 0; r < 4; r++)
#pragma unroll
        for (int s = 0; s < 8; s++) red[tile][lane][r*8 + s] = o[g][r][s];
    }
    __syncthreads();
    if (wave < 4) {
#pragma unroll
      for (int r = 0; r < 4; r++) {
        int cout = tile*16 + ((lane >> 4) << 2) + r;
        float bv = biasb[((size_t)b*BCH_ + layer*2*C_ + cout)*LMEL_ + l0 + g*16 + f];
#pragma unroll
        for (int s = 0; s < 8; s++)
          o[g][r][s] += red[tile][lane][r*8 + s] + bv;
      }
      if (wave >= 2) {
#pragma unroll
        for (int r = 0; r < 4; r++)
#pragma unroll
          for (int s = 0; s < 8; s++) red[tile][lane][r*8 + s] = o[g][r][s];
      }
    }
    __syncthreads();
    if (wave < 2) {
#pragma unroll
      for (int r = 0; r < 4; r++) {
        int cout = tile*16 + ((lane >> 4) << 2) + r;   // 0..31
        size_t base = ((size_t)b*C_ + cout)*LAUD_ + (size_t)(l0 + g*16 + f)*HOP_;
        float4 h0 = *reinterpret_cast<const float4*>(&h[base]);
        float4 h1 = *reinterpret_cast<const float4*>(&h[base + 4]);
        float4 a0 = *reinterpret_cast<const float4*>(&ad[base]);
        float4 a1 = *reinterpret_cast<const float4*>(&ad[base + 4]);
        float out[8];
#pragma unroll
        for (int s = 0; s < 8; s++) {
          float v  = o[g][r][s];
          float tv = red[tile + 2][lane][r*8 + s];
          float sig = 1.f / (1.f + __expf(-v));
          float th  = 1.f - 2.f / (1.f + __expf(2.f*tv));
          float hv = (s < 4) ? ((const float*)&h0)[s] : ((const float*)&h1)[s-4];
          float av = (s < 4) ? ((const float*)&a0)[s] : ((const float*)&a1)[s-4];
          out[s] = hv + av + sig * th;
        }
        *reinterpret_cast<float4*>(&h[base])     = make_float4(out[0], out[1], out[2], out[3]);
        *reinterpret_cast<float4*>(&h[base + 4]) = make_float4(out[4], out[5], out[6], out[7]);
      }
    }
  }
}

// ---------------------------------------------------------------- launcher
extern "C" void kernel_launch(void* const* d_in, const int* in_sizes, int n_in,
                              void* d_out, int out_size, void* d_ws, size_t ws_size,
                              hipStream_t stream) {
  const float* x     = (const float*)d_in[0];
  const float* ad    = (const float*)d_in[1];
  const float* c     = (const float*)d_in[2];
  const float* ne    = (const float*)d_in[3];
  const float* fw    = (const float*)d_in[4];
  const float* fb    = (const float*)d_in[5];
  const float* upw   = (const float*)d_in[6];
  const float* convw = (const float*)d_in[7];
  const float* kinw  = (const float*)d_in[8];
  const float* kinb  = (const float*)d_in[9];
  const float* krw1  = (const float*)d_in[10];
  const float* krb1  = (const float*)d_in[11];
  const float* krw2  = (const float*)d_in[12];
  const float* krb2  = (const float*)d_in[13];
  const float* kkw   = (const float*)d_in[14];
  const float* kkb   = (const float*)d_in[15];
  const float* kbw   = (const float*)d_in[16];
  const float* kbb   = (const float*)d_in[17];
  float* h = (float*)d_out;

  float* ws = (float*)d_ws;
  float* cond  = ws; ws += B_*COND_*LMEL_;
  float* hkpa  = ws; ws += B_*HID_*LMEL_;
  float* hkpb  = ws; ws += B_*HID_*LMEL_;
  float* biasb = ws; ws += B_*BCH_*LMEL_;
  float* y2    = ws; ws += B_*C_*LAUD_;
  float* kbt   = ws; ws += KCH_;
  float* wtup  = ws; ws += C_*C_*16;
  unsigned short* waf = (unsigned short*)ws; ws += (KCH_*HID_*KPK_)/2;

  k_mkA<<<(KCH_*HID_*KPK_ + 255)/256, 256, 0, stream>>>(kkw, waf);
  k_mkKbT<<<(KCH_ + 255)/256, 256, 0, stream>>>(kkb, kbt);
  k_mkUp<<<(C_*C_*16 + 255)/256, 256, 0, stream>>>(upw, wtup);
  k_noise_cond<<<B_*COND_, 256, 0, stream>>>(ne, fw, fb, c, cond);
  k_kp_in<<<B_*(LMEL_/32), 256, 0, stream>>>(cond, kinw, kinb, hkpa);
  for (int i = 0; i < 3; i++) {
    k_kp_res<<<B_*(LMEL_/32), 256, 0, stream>>>(hkpa, krw1 + i*HID_*HID_*3, krb1 + i*HID_, nullptr, hkpb);
    k_kp_res<<<B_*(LMEL_/32), 256, 0, stream>>>(hkpb, krw2 + i*HID_*HID_*3, krb2 + i*HID_, hkpa, hkpa);
  }
  k_kp_bias<<<B_*(LMEL_/16), 256, 0, stream>>>(hkpa, kbw, kbb, biasb);
  k_upsample<<<B_*65, 256, 0, stream>>>(x, wtup, h);

  for (int i = 0; i < LAYERS_; i++) {
    const float* wci = convw + i*C_*C_*3;
    switch (i) {
      case 0: k_dilconv<1 ><<<B_*(LAUD_/128), 256, 0, stream>>>(h, ad, wci, y2); break;
      case 1: k_dilconv<3 ><<<B_*(LAUD_/128), 256, 0, stream>>>(h, ad, wci, y2); break;
      case 2: k_dilconv<9 ><<<B_*(LAUD_/128), 256, 0, stream>>>(h, ad, wci, y2); break;
      case 3: k_dilconv<27><<<B_*(LAUD_/128), 256, 0, stream>>>(h, ad, wci, y2); break;
    }
    k_lvc_mfma<<<B_*(LMEL_/FR2), 512, 0, stream>>>(hkpa, waf, kbt, biasb, y2, ad, h, i);
  }
}

// Round 4
// 483.121 us; speedup vs baseline: 14.5000x; 1.1177x over previous
//
#include <hip/hip_runtime.h>
#include <math.h>

#define B_      4
#define C_      32
#define COND_   80
#define LMEL_   2048
#define HOP_    8
#define UP_     8
#define LAYERS_ 4
#define K_      3
#define HID_    64
#define KPK_    3
#define EMB_    512
#define LAUD_   (LMEL_*UP_)          // 16384
#define KCH_    (LAYERS_*C_*2*C_*K_) // 24576
#define BCH_    (LAYERS_*2*C_)       // 256

typedef short v8s __attribute__((ext_vector_type(8)));
typedef float v4f __attribute__((ext_vector_type(4)));

__device__ __forceinline__ float lrelu_(float v, float s) { return v >= 0.f ? v : s * v; }

__device__ __forceinline__ unsigned short f2bf(float f) {  // RNE float->bf16
  unsigned int x = __float_as_uint(f);
  unsigned int r = (x + 0x7FFFu + ((x >> 16) & 1u)) >> 16;
  return (unsigned short)r;
}

// ---------------------------------------------------------------- K1: noise + condition
__global__ void k_noise_cond(const float* __restrict__ ne, const float* __restrict__ fw,
                             const float* __restrict__ fb, const float* __restrict__ c,
                             float* __restrict__ cond) {
  int b = blockIdx.x / COND_;
  int cc = blockIdx.x % COND_;
  __shared__ float red[256];
  float p = 0.f;
  for (int j = threadIdx.x; j < EMB_; j += 256)
    p += ne[b*EMB_ + j] * fw[cc*EMB_ + j];
  red[threadIdx.x] = p;
  __syncthreads();
  for (int s = 128; s > 0; s >>= 1) {
    if (threadIdx.x < s) red[threadIdx.x] += red[threadIdx.x + s];
    __syncthreads();
  }
  float noise = red[0] + fb[cc];
  const float* cp = c + (b*COND_ + cc)*LMEL_;
  float* op = cond + (b*COND_ + cc)*LMEL_;
  for (int l = threadIdx.x; l < LMEL_; l += 256) op[l] = cp[l] + noise;
}

// ---------------------------------------------------------------- K2: KP input conv (80->64, k=5, pad=2, lrelu 0.1), T=32
__global__ __launch_bounds__(256) void k_kp_in(const float* __restrict__ cond, const float* __restrict__ w,
                                               const float* __restrict__ bias, float* __restrict__ out) {
  const int T = 32;
  int b  = blockIdx.x / (LMEL_/T);
  int lb = (blockIdx.x % (LMEL_/T)) * T;
  __shared__ float sc[COND_][T + 4];
  for (int idx = threadIdx.x; idx < COND_*(T+4); idx += 256) {
    int cc = idx / (T+4), j = idx % (T+4);
    int l = lb + j - 2;
    sc[cc][j] = (l >= 0 && l < LMEL_) ? cond[(b*COND_ + cc)*LMEL_ + l] : 0.f;
  }
  __syncthreads();
  int ch = threadIdx.x & 63;
  int lq = threadIdx.x >> 6;  // 0..3, 8 l's each
  float acc[8];
#pragma unroll
  for (int ii = 0; ii < 8; ii++) acc[ii] = bias[ch];
  const float* wr = w + ch*COND_*5;
  for (int cc = 0; cc < COND_; cc++) {
    float r[12];
#pragma unroll
    for (int j = 0; j < 12; j++) r[j] = sc[cc][lq*8 + j];
#pragma unroll
    for (int k = 0; k < 5; k++) {
      float wv = wr[cc*5 + k];
#pragma unroll
      for (int ii = 0; ii < 8; ii++) acc[ii] = fmaf(wv, r[ii + k], acc[ii]);
    }
  }
  float* op = out + (b*HID_ + ch)*LMEL_ + lb + lq*8;
#pragma unroll
  for (int ii = 0; ii < 8; ii++) acc[ii] = lrelu_(acc[ii], 0.1f);
  *reinterpret_cast<float4*>(&op[0]) = make_float4(acc[0], acc[1], acc[2], acc[3]);
  *reinterpret_cast<float4*>(&op[4]) = make_float4(acc[4], acc[5], acc[6], acc[7]);
}

// ---------------------------------------------------------------- K3: KP res conv (64->64, k=3, pad=1, lrelu 0.1, opt residual), T=32
__global__ __launch_bounds__(256) void k_kp_res(const float* __restrict__ in, const float* __restrict__ w,
                                                const float* __restrict__ bias, const float* __restrict__ res,
                                                float* __restrict__ out) {
  const int T = 32;
  int b  = blockIdx.x / (LMEL_/T);
  int lb = (blockIdx.x % (LMEL_/T)) * T;
  __shared__ float si[HID_][T + 4];
  for (int idx = threadIdx.x; idx < HID_*(T+2); idx += 256) {
    int cc = idx / (T+2), j = idx % (T+2);
    int l = lb + j - 1;
    si[cc][j] = (l >= 0 && l < LMEL_) ? in[(b*HID_ + cc)*LMEL_ + l] : 0.f;
  }
  __syncthreads();
  int ch = threadIdx.x & 63;
  int lq = threadIdx.x >> 6;
  float acc[8];
#pragma unroll
  for (int ii = 0; ii < 8; ii++) acc[ii] = bias[ch];
  const float* wr = w + ch*HID_*3;
  for (int cc = 0; cc < HID_; cc++) {
    float r[10];
#pragma unroll
    for (int j = 0; j < 10; j++) r[j] = si[cc][lq*8 + j];
#pragma unroll
    for (int k = 0; k < 3; k++) {
      float wv = wr[cc*3 + k];
#pragma unroll
      for (int ii = 0; ii < 8; ii++) acc[ii] = fmaf(wv, r[ii + k], acc[ii]);
    }
  }
  int lo = lb + lq*8;
  float* op = out + (b*HID_ + ch)*LMEL_ + lo;
  const float* rp = res ? res + (b*HID_ + ch)*LMEL_ + lo : nullptr;
#pragma unroll
  for (int ii = 0; ii < 8; ii++) {
    acc[ii] = lrelu_(acc[ii], 0.1f);
    if (rp) acc[ii] += rp[ii];
  }
  *reinterpret_cast<float4*>(&op[0]) = make_float4(acc[0], acc[1], acc[2], acc[3]);
  *reinterpret_cast<float4*>(&op[4]) = make_float4(acc[4], acc[5], acc[6], acc[7]);
}

// ---------------------------------------------------------------- K4: bias conv (64->256, k=3, pad=1), T=16
__global__ __launch_bounds__(256) void k_kp_bias(const float* __restrict__ in, const float* __restrict__ w,
                                                 const float* __restrict__ bias, float* __restrict__ out) {
  const int T = 16;
  int b  = blockIdx.x / (LMEL_/T);
  int lb = (blockIdx.x % (LMEL_/T)) * T;
  __shared__ float si[HID_][T + 2];
  for (int idx = threadIdx.x; idx < HID_*(T+2); idx += 256) {
    int cc = idx / (T+2), j = idx % (T+2);
    int l = lb + j - 1;
    si[cc][j] = (l >= 0 && l < LMEL_) ? in[(b*HID_ + cc)*LMEL_ + l] : 0.f;
  }
  __syncthreads();
  int ch = threadIdx.x;  // 0..255
  float acc[T];
  float bv = bias[ch];
#pragma unroll
  for (int ii = 0; ii < T; ii++) acc[ii] = bv;
  const float* wr = w + ch*HID_*3;
  for (int cc = 0; cc < HID_; cc++) {
    float w0 = wr[cc*3], w1 = wr[cc*3+1], w2 = wr[cc*3+2];
#pragma unroll
    for (int ii = 0; ii < T; ii++)
      acc[ii] = fmaf(w0, si[cc][ii], fmaf(w1, si[cc][ii+1], fmaf(w2, si[cc][ii+2], acc[ii])));
  }
  float* op = out + (b*BCH_ + ch)*LMEL_ + lb;
#pragma unroll
  for (int q = 0; q < 4; q++)
    *reinterpret_cast<float4*>(&op[q*4]) = make_float4(acc[q*4], acc[q*4+1], acc[q*4+2], acc[q*4+3]);
}

// ---------------------------------------------------------------- prep: upsample weight transpose -> wt[(ci*16+j)*32+co]
__global__ void k_mkUp(const float* __restrict__ upw, float* __restrict__ wt) {
  int idx = blockIdx.x*256 + threadIdx.x;
  if (idx >= C_*C_*16) return;
  int co = idx & 31, j = (idx >> 5) & 15, ci = idx >> 9;
  wt[idx] = upw[(ci*C_ + co)*16 + j];
}

// ---------------------------------------------------------------- K5: upsample (conv_transpose1d stride 8, k=16, pad=4), lrelu(x,0.2) input
#define UT 32
__global__ __launch_bounds__(256) void k_upsample(const float* __restrict__ x, const float* __restrict__ wt,
                                                  float* __restrict__ h) {
  int b  = blockIdx.x / 65;
  int s0 = (blockIdx.x % 65) * UT;
  __shared__ float sw[16384];          // [ci][j][co]
  __shared__ float sx[C_][33 + 3];
  for (int idx = threadIdx.x*4; idx < 16384; idx += 1024)
    *reinterpret_cast<float4*>(&sw[idx]) = *reinterpret_cast<const float4*>(&wt[idx]);
  for (int idx = threadIdx.x; idx < C_*33; idx += 256) {
    int ci = idx / 33, i = idx % 33;
    int s = s0 - 1 + i;
    float v = (s >= 0 && s < LMEL_) ? x[(b*C_ + ci)*LMEL_ + s] : 0.f;
    sx[ci][i] = lrelu_(v, 0.2f);
  }
  __syncthreads();
  int co = threadIdx.x & 31, sq = threadIdx.x >> 5;  // sq 0..7, 4 frames each
  float acc[4][8];
#pragma unroll
  for (int k = 0; k < 4; k++)
#pragma unroll
    for (int r = 0; r < 8; r++) acc[k][r] = 0.f;
  for (int ci = 0; ci < C_; ci++) {
    float xv[5];
#pragma unroll
    for (int m = 0; m < 5; m++) xv[m] = sx[ci][sq*4 + m];
    const float* wl = &sw[ci*512 + co];
#pragma unroll
    for (int r = 0; r < 8; r++) {
      float wa = wl[r*32];
      float wb = wl[(r+8)*32];
#pragma unroll
      for (int k = 0; k < 4; k++)
        acc[k][r] = fmaf(wa, xv[k+1], fmaf(wb, xv[k], acc[k][r]));
    }
  }
  float* op = h + ((size_t)b*C_ + co)*LAUD_;
#pragma unroll
  for (int k = 0; k < 4; k++) {
    int s1 = s0 + sq*4 + k;
    int lo = 8*s1 - 4;
    if (lo >= 0 && lo + 4 <= LAUD_)
      *reinterpret_cast<float4*>(&op[lo]) = make_float4(acc[k][0], acc[k][1], acc[k][2], acc[k][3]);
    if (lo >= -4 && lo + 8 <= LAUD_)
      *reinterpret_cast<float4*>(&op[lo+4]) = make_float4(acc[k][4], acc[k][5], acc[k][6], acc[k][7]);
  }
}

// ---------------------------------------------------------------- prep: A-fragment-ordered bf16 weights
__global__ void k_mkA(const float* __restrict__ kw, unsigned short* __restrict__ waf) {
  int idx = blockIdx.x*256 + threadIdx.x;
  if (idx >= KCH_*HID_*KPK_) return;   // 4,718,592
  int i    = idx & 7;
  int lane = (idx >> 3) & 63;
  int ks   = (idx >> 9) % 6;
  int tile = (idx / 3072) & 3;
  int rk   = idx / 12288;              // 0..383
  int layer = rk / 96, rem = rk % 96, ci = rem / 3, kk = rem % 3;
  int cout = tile*16 + (lane & 15);
  int j    = ks*32 + ((lane >> 4) << 3) + i;
  int row  = ((layer*32 + ci)*64 + cout)*3 + kk;
  waf[idx] = f2bf(kw[row*192 + j]);
}

// ---------------------------------------------------------------- prep: kernel-conv bias reordered
__global__ void k_mkKbT(const float* __restrict__ kb, float* __restrict__ kbt) {
  int idx = blockIdx.x*256 + threadIdx.x;
  if (idx >= KCH_) return;             // 24576
  int cr = idx & 15, tile = (idx >> 4) & 3, rk = idx >> 6;
  int layer = rk / 96, rem = rk % 96, ci = rem / 3, kk = rem % 3;
  int cout = tile*16 + cr;
  kbt[idx] = kb[((layer*32 + ci)*64 + cout)*3 + kk];
}

// ---------------------------------------------------------------- K6: dilated conv (32->32, k=3) on lrelu(h+ad,0.2), out lrelu 0.2, T=128
template<int DIL>
__global__ __launch_bounds__(256) void k_dilconv(const float* __restrict__ h, const float* __restrict__ ad,
                                                 const float* __restrict__ w, float* __restrict__ y2) {
  const int T = 128;
  int b  = blockIdx.x / (LAUD_/T);
  int tb = (blockIdx.x % (LAUD_/T)) * T;
  const int W = T + 2*DIL;
  __shared__ float ss[C_][T + 2*27 + 4];
  for (int idx = threadIdx.x; idx < C_*W; idx += 256) {
    int ci = idx / W, j = idx % W;
    int t = tb - DIL + j;
    float v = 0.f;
    if (t >= 0 && t < LAUD_) {
      int g = (b*C_ + ci)*LAUD_ + t;
      v = h[g] + ad[g];
    }
    ss[ci][j] = lrelu_(v, 0.2f);
  }
  __syncthreads();
  int co = threadIdx.x & 31, tq = threadIdx.x >> 5;
  float acc[16];
#pragma unroll
  for (int ii = 0; ii < 16; ii++) acc[ii] = 0.f;
  const float* wr = w + co*C_*3;
  for (int ci = 0; ci < C_; ci++) {
    float w0 = wr[ci*3], w1 = wr[ci*3+1], w2 = wr[ci*3+2];
#pragma unroll
    for (int ii = 0; ii < 16; ii++) {
      int tl = tq*16 + ii;
      acc[ii] = fmaf(w0, ss[ci][tl], fmaf(w1, ss[ci][tl + DIL], fmaf(w2, ss[ci][tl + 2*DIL], acc[ii])));
    }
  }
  float* op = y2 + (b*C_ + co)*LAUD_ + tb + tq*16;
#pragma unroll
  for (int ii = 0; ii < 16; ii++) acc[ii] = lrelu_(acc[ii], 0.2f);
#pragma unroll
  for (int q = 0; q < 4; q++)
    *reinterpret_cast<float4*>(&op[q*4]) = make_float4(acc[q*4], acc[q*4+1], acc[q*4+2], acc[q*4+3]);
}

// ---------------------------------------------------------------- K7: MFMA-fused KP-GEMM + LVC + gate + h update, FPW=2 (32 frames/block)
// Accumulators split into NAMED arrays o0/o1 (rule #20: no runtime-indexed
// register arrays), epilogue via compile-time-G macro.
#define FR2 32

#define EPILOGUE(G, OO)                                                          \
  {                                                                              \
    if (G) __syncthreads();                                                      \
    if (wave >= 4) {                                                             \
      _Pragma("unroll") for (int r = 0; r < 4; r++)                              \
        _Pragma("unroll") for (int s = 0; s < 8; s++)                            \
          red[tile][lane][r*8 + s] = OO[r][s];                                   \
    }                                                                            \
    __syncthreads();                                                             \
    if (wave < 4) {                                                              \
      _Pragma("unroll") for (int r = 0; r < 4; r++) {                            \
        int cout = tile*16 + ((lane >> 4) << 2) + r;                             \
        float bv = biasb[((size_t)b*BCH_ + layer*2*C_ + cout)*LMEL_ + l0 + G*16 + f]; \
        _Pragma("unroll") for (int s = 0; s < 8; s++)                            \
          OO[r][s] += red[tile][lane][r*8 + s] + bv;                             \
      }                                                                          \
      if (wave >= 2) {                                                           \
        _Pragma("unroll") for (int r = 0; r < 4; r++)                            \
          _Pragma("unroll") for (int s = 0; s < 8; s++)                          \
            red[tile][lane][r*8 + s] = OO[r][s];                                 \
      }                                                                          \
    }                                                                            \
    __syncthreads();                                                             \
    if (wave < 2) {                                                              \
      _Pragma("unroll") for (int r = 0; r < 4; r++) {                            \
        int cout = tile*16 + ((lane >> 4) << 2) + r;                             \
        size_t base = ((size_t)b*C_ + cout)*LAUD_ + (size_t)(l0 + G*16 + f)*HOP_;\
        float4 h0 = *reinterpret_cast<const float4*>(&h[base]);                  \
        float4 h1 = *reinterpret_cast<const float4*>(&h[base + 4]);              \
        float4 a0 = *reinterpret_cast<const float4*>(&ad[base]);                 \
        float4 a1 = *reinterpret_cast<const float4*>(&ad[base + 4]);             \
        float outv[8];                                                           \
        _Pragma("unroll") for (int s = 0; s < 8; s++) {                          \
          float v  = OO[r][s];                                                   \
          float tv = red[tile + 2][lane][r*8 + s];                               \
          float sig = 1.f / (1.f + __expf(-v));                                  \
          float th  = 1.f - 2.f / (1.f + __expf(2.f*tv));                        \
          float hv = (s < 4) ? ((const float*)&h0)[s] : ((const float*)&h1)[s-4];\
          float av = (s < 4) ? ((const float*)&a0)[s] : ((const float*)&a1)[s-4];\
          outv[s] = hv + av + sig * th;                                          \
        }                                                                        \
        *reinterpret_cast<float4*>(&h[base])     = make_float4(outv[0], outv[1], outv[2], outv[3]); \
        *reinterpret_cast<float4*>(&h[base + 4]) = make_float4(outv[4], outv[5], outv[6], outv[7]); \
      }                                                                          \
    }                                                                            \
  }

__global__ __launch_bounds__(512, 2) void k_lvc_mfma(
    const float* __restrict__ hkp, const unsigned short* __restrict__ waf,
    const float* __restrict__ kbt, const float* __restrict__ biasb,
    const float* __restrict__ y2, const float* __restrict__ ad,
    float* __restrict__ h, int layer) {
  int b  = blockIdx.x >> 6;               // 64 frame-tiles of 32
  int l0 = (blockIdx.x & 63) * FR2;

  __shared__ __align__(16) float sy[C_][FR2*HOP_ + 4];     // 260 stride, 258 used
  __shared__ __align__(16) float shh[HID_][36];            // 34 used
  __shared__ __align__(16) unsigned short FB[2*6*64*8];    // B frags, 2 tiles x 6 ksteps
  __shared__ float red[4][64][33];

  int tid = threadIdx.x;
  for (int idx = tid; idx < C_*(FR2*HOP_+2); idx += 512) {
    int ci = idx / (FR2*HOP_+2), j = idx % (FR2*HOP_+2);
    int t = l0*HOP_ - 1 + j;
    sy[ci][j] = (t >= 0 && t < LAUD_) ? y2[(b*C_ + ci)*LAUD_ + t] : 0.f;
  }
  for (int idx = tid; idx < HID_*34; idx += 512) {
    int hh = idx / 34, j = idx % 34;
    int l = l0 - 1 + j;
    shh[hh][j] = (l >= 0 && l < LMEL_) ? hkp[(b*HID_ + hh)*LMEL_ + l] : 0.f;
  }
  __syncthreads();
  // build B fragments for both 16-frame sub-tiles
  for (int idx = tid; idx < 6144; idx += 512) {
    int i = idx & 7, lane2 = (idx >> 3) & 63, gk = idx >> 9;  // gk = g*6+ks
    int ks = gk % 6, g = gk / 6;
    int k = ks*32 + ((lane2 >> 4) << 3) + i;
    int col = lane2 & 15;
    int hh = k / 3, q = k - hh*3;
    FB[idx] = f2bf(shh[hh][g*16 + col + q]);
  }
  __syncthreads();

  int wave = tid >> 6, lane = tid & 63;
  int tile = wave & 3, cihalf = wave >> 2;
  int f = lane & 15;

  v8s bfrA[6], bfrB[6];
#pragma unroll
  for (int ks = 0; ks < 6; ks++) {
    bfrA[ks] = *reinterpret_cast<const v8s*>(&FB[(ks*64 + lane)*8]);
    bfrB[ks] = *reinterpret_cast<const v8s*>(&FB[((6 + ks)*64 + lane)*8]);
  }

  float o0[4][8], o1[4][8];
#pragma unroll
  for (int r = 0; r < 4; r++)
#pragma unroll
    for (int s = 0; s < 8; s++) { o0[r][s] = 0.f; o1[r][s] = 0.f; }

  const int rk0 = layer*96 + cihalf*48;
  const unsigned short* wbase = waf + ((size_t)rk0*4 + tile)*3072 + lane*8;
  const float* kbbase = kbt + (rk0*4 + tile)*16 + ((lane >> 4) << 2);

  for (int ci16 = 0; ci16 < 16; ci16++) {
    int ci = cihalf*16 + ci16;
    float syr0[12], syr1[12];
    {
      float4 s0 = *reinterpret_cast<const float4*>(&sy[ci][f*8]);
      float4 s1 = *reinterpret_cast<const float4*>(&sy[ci][f*8 + 4]);
      float4 s2 = *reinterpret_cast<const float4*>(&sy[ci][f*8 + 8]);
      syr0[0]=s0.x; syr0[1]=s0.y; syr0[2]=s0.z; syr0[3]=s0.w;
      syr0[4]=s1.x; syr0[5]=s1.y; syr0[6]=s1.z; syr0[7]=s1.w;
      syr0[8]=s2.x; syr0[9]=s2.y; syr0[10]=s2.z; syr0[11]=s2.w;
      float4 t0 = *reinterpret_cast<const float4*>(&sy[ci][(16 + f)*8]);
      float4 t1 = *reinterpret_cast<const float4*>(&sy[ci][(16 + f)*8 + 4]);
      float4 t2 = *reinterpret_cast<const float4*>(&sy[ci][(16 + f)*8 + 8]);
      syr1[0]=t0.x; syr1[1]=t0.y; syr1[2]=t0.z; syr1[3]=t0.w;
      syr1[4]=t1.x; syr1[5]=t1.y; syr1[6]=t1.z; syr1[7]=t1.w;
      syr1[8]=t2.x; syr1[9]=t2.y; syr1[10]=t2.z; syr1[11]=t2.w;
    }
#pragma unroll
    for (int kk = 0; kk < 3; kk++) {
      const unsigned short* wp = wbase + (size_t)(ci16*3 + kk)*12288;
      v4f acc0 = {0.f, 0.f, 0.f, 0.f};
      v4f acc1 = {0.f, 0.f, 0.f, 0.f};
#pragma unroll
      for (int ks = 0; ks < 6; ks++) {
        v8s a = *reinterpret_cast<const v8s*>(wp + ks*512);
        acc0 = __builtin_amdgcn_mfma_f32_16x16x32_bf16(a, bfrA[ks], acc0, 0, 0, 0);
        acc1 = __builtin_amdgcn_mfma_f32_16x16x32_bf16(a, bfrB[ks], acc1, 0, 0, 0);
      }
      float4 kb4 = *reinterpret_cast<const float4*>(kbbase + (ci16*3 + kk)*64);
#pragma unroll
      for (int r = 0; r < 4; r++) {
        float k0 = acc0[r] + ((const float*)&kb4)[r];
        float k1 = acc1[r] + ((const float*)&kb4)[r];
#pragma unroll
        for (int s = 0; s < 8; s++) {
          o0[r][s] = fmaf(k0, syr0[kk + s], o0[r][s]);
          o1[r][s] = fmaf(k1, syr1[kk + s], o1[r][s]);
        }
      }
    }
  }

  EPILOGUE(0, o0)
  EPILOGUE(1, o1)
}

// ---------------------------------------------------------------- launcher
extern "C" void kernel_launch(void* const* d_in, const int* in_sizes, int n_in,
                              void* d_out, int out_size, void* d_ws, size_t ws_size,
                              hipStream_t stream) {
  const float* x     = (const float*)d_in[0];
  const float* ad    = (const float*)d_in[1];
  const float* c     = (const float*)d_in[2];
  const float* ne    = (const float*)d_in[3];
  const float* fw    = (const float*)d_in[4];
  const float* fb    = (const float*)d_in[5];
  const float* upw   = (const float*)d_in[6];
  const float* convw = (const float*)d_in[7];
  const float* kinw  = (const float*)d_in[8];
  const float* kinb  = (const float*)d_in[9];
  const float* krw1  = (const float*)d_in[10];
  const float* krb1  = (const float*)d_in[11];
  const float* krw2  = (const float*)d_in[12];
  const float* krb2  = (const float*)d_in[13];
  const float* kkw   = (const float*)d_in[14];
  const float* kkb   = (const float*)d_in[15];
  const float* kbw   = (const float*)d_in[16];
  const float* kbb   = (const float*)d_in[17];
  float* h = (float*)d_out;

  float* ws = (float*)d_ws;
  float* cond  = ws; ws += B_*COND_*LMEL_;
  float* hkpa  = ws; ws += B_*HID_*LMEL_;
  float* hkpb  = ws; ws += B_*HID_*LMEL_;
  float* biasb = ws; ws += B_*BCH_*LMEL_;
  float* y2    = ws; ws += B_*C_*LAUD_;
  float* kbt   = ws; ws += KCH_;
  float* wtup  = ws; ws += C_*C_*16;
  unsigned short* waf = (unsigned short*)ws; ws += (KCH_*HID_*KPK_)/2;

  k_mkA<<<(KCH_*HID_*KPK_ + 255)/256, 256, 0, stream>>>(kkw, waf);
  k_mkKbT<<<(KCH_ + 255)/256, 256, 0, stream>>>(kkb, kbt);
  k_mkUp<<<(C_*C_*16 + 255)/256, 256, 0, stream>>>(upw, wtup);
  k_noise_cond<<<B_*COND_, 256, 0, stream>>>(ne, fw, fb, c, cond);
  k_kp_in<<<B_*(LMEL_/32), 256, 0, stream>>>(cond, kinw, kinb, hkpa);
  for (int i = 0; i < 3; i++) {
    k_kp_res<<<B_*(LMEL_/32), 256, 0, stream>>>(hkpa, krw1 + i*HID_*HID_*3, krb1 + i*HID_, nullptr, hkpb);
    k_kp_res<<<B_*(LMEL_/32), 256, 0, stream>>>(hkpb, krw2 + i*HID_*HID_*3, krb2 + i*HID_, hkpa, hkpa);
  }
  k_kp_bias<<<B_*(LMEL_/16), 256, 0, stream>>>(hkpa, kbw, kbb, biasb);
  k_upsample<<<B_*65, 256, 0, stream>>>(x, wtup, h);

  for (int i = 0; i < LAYERS_; i++) {
    const float* wci = convw + i*C_*C_*3;
    switch (i) {
      case 0: k_dilconv<1 ><<<B_*(LAUD_/128), 256, 0, stream>>>(h, ad, wci, y2); break;
      case 1: k_dilconv<3 ><<<B_*(LAUD_/128), 256, 0, stream>>>(h, ad, wci, y2); break;
      case 2: k_dilconv<9 ><<<B_*(LAUD_/128), 256, 0, stream>>>(h, ad, wci, y2); break;
      case 3: k_dilconv<27><<<B_*(LAUD_/128), 256, 0, stream>>>(h, ad, wci, y2); break;
    }
    k_lvc_mfma<<<B_*(LMEL_/FR2), 512, 0, stream>>>(hkpa, waf, kbt, biasb, y2, ad, h, i);
  }
}